// Round 11
// baseline (791.040 us; speedup 1.0000x reference)
//
#include <hip/hip_runtime.h>
#include <stdint.h>

#define H_DIM 2048
#define N_TOK 4096
#define I_DIM 8192

typedef __attribute__((ext_vector_type(8))) short short8;
typedef __attribute__((ext_vector_type(4))) float f32x4;

typedef const __attribute__((address_space(1))) unsigned int* gp_t;
typedef __attribute__((address_space(3))) unsigned int* lp_t;

__device__ __forceinline__ void gload16(const unsigned short* g, short* l) {
    __builtin_amdgcn_global_load_lds((gp_t)g, (lp_t)l, 16, 0, 0);
}

__device__ __forceinline__ unsigned short f2bf(float f) {
    union { float f; unsigned int u; } c; c.f = f;
    unsigned int u = c.u;
    return (unsigned short)((u + 0x7FFFu + ((u >> 16) & 1u)) >> 16);  // RNE
}
__device__ __forceinline__ float bf2f(unsigned short u) {
    union { unsigned int i; float f; } c; c.i = ((unsigned int)u) << 16;
    return c.f;
}

__device__ __forceinline__ float wmax64(float v) {
#pragma unroll
    for (int o = 32; o > 0; o >>= 1) v = fmaxf(v, __shfl_xor(v, o));
    return v;
}
__device__ __forceinline__ float wsum64(float v) {
#pragma unroll
    for (int o = 32; o > 0; o >>= 1) v += __shfl_xor(v, o);
    return v;
}

template<int K, int RSTEP, int LSTEP>
__device__ __forceinline__ void stage4(const unsigned short* src, short* dst) {
#pragma unroll
    for (int j = 0; j < 4; ++j)
        gload16(src + (size_t)j * RSTEP * K, dst + j * LSTEP);
}
template<int K, int RSTEP, int LSTEP>
__device__ __forceinline__ void stage2(const unsigned short* src, short* dst) {
#pragma unroll
    for (int j = 0; j < 2; ++j)
        gload16(src + (size_t)j * RSTEP * K, dst + j * LSTEP);
}

// ---------------- BatchNorm statistics (deterministic 2-stage) ----------------
__global__ __launch_bounds__(256) void bn_stats(const float* __restrict__ x,
                                                float* __restrict__ ps, float* __restrict__ pq) {
    int col = blockIdx.x * 256 + threadIdx.x;
    int r0  = blockIdx.y * 128;
    float s = 0.f, q = 0.f;
    for (int r = 0; r < 128; ++r) {
        float v = x[(size_t)(r0 + r) * H_DIM + col];
        s += v; q += v * v;
    }
    ps[blockIdx.y * H_DIM + col] = s;
    pq[blockIdx.y * H_DIM + col] = q;
}

__global__ __launch_bounds__(256) void bn_finalize(const float* __restrict__ ps, const float* __restrict__ pq,
                                                   float* __restrict__ mu, float* __restrict__ rsig) {
    int c = blockIdx.x * 256 + threadIdx.x;
    float s = 0.f, q = 0.f;
    for (int i = 0; i < 32; ++i) { s += ps[i * H_DIM + c]; q += pq[i * H_DIM + c]; }
    float m = s * (1.f / N_TOK);
    float v = q * (1.f / N_TOK) - m * m;
    mu[c] = m;
    rsig[c] = rsqrtf(v + 1e-5f);
}

// ---------------- one-shot f32 -> bf16 conversion of everything -------------
__global__ __launch_bounds__(256) void cvt_all(const float* __restrict__ gw, const float* __restrict__ uw,
                                               const float* __restrict__ dw, const float* __restrict__ de,
                                               const float* __restrict__ ue, const float* __restrict__ x,
                                               unsigned short* __restrict__ gwb, unsigned short* __restrict__ uwb,
                                               unsigned short* __restrict__ dwb, unsigned short* __restrict__ deb,
                                               unsigned short* __restrict__ ueb, unsigned short* __restrict__ xb) {
    int b = blockIdx.x;
    const float* src; unsigned short* dst; size_t base;
    if      (b < 8192)  { src = gw; dst = gwb; base = (size_t)b; }
    else if (b < 16384) { src = uw; dst = uwb; base = (size_t)(b - 8192); }
    else if (b < 24576) { src = dw; dst = dwb; base = (size_t)(b - 16384); }
    else if (b < 28672) { src = de; dst = deb; base = (size_t)(b - 24576); }
    else if (b < 32768) { src = ue; dst = ueb; base = (size_t)(b - 28672); }
    else                { src = x;  dst = xb;  base = (size_t)(b - 32768); }
    size_t off = (base * 256 + threadIdx.x) * 8;
    float4 a = *(const float4*)(src + off);
    float4 c = *(const float4*)(src + off + 4);
    short8 s;
    s[0]=(short)f2bf(a.x); s[1]=(short)f2bf(a.y); s[2]=(short)f2bf(a.z); s[3]=(short)f2bf(a.w);
    s[4]=(short)f2bf(c.x); s[5]=(short)f2bf(c.y); s[6]=(short)f2bf(c.z); s[7]=(short)f2bf(c.w);
    *(short8*)(dst + off) = s;
}

// ---------------- x -> bf16 (fallback path only) ----------------
__global__ __launch_bounds__(256) void cvt_x(const float* __restrict__ x, unsigned short* __restrict__ xb) {
    size_t i = ((size_t)blockIdx.x * 256 + threadIdx.x) * 4;
    float4 v = *(const float4*)(x + i);
    uint2 o;
    o.x = (unsigned)f2bf(v.x) | ((unsigned)f2bf(v.y) << 16);
    o.y = (unsigned)f2bf(v.z) | ((unsigned)f2bf(v.w) << 16);
    *(uint2*)(xb + i) = o;
}

__global__ __launch_bounds__(256) void cvt_w(const float* __restrict__ src, unsigned short* __restrict__ dst) {
    size_t off = ((size_t)blockIdx.x * 256 + threadIdx.x) * 8;
    float4 a = *(const float4*)(src + off);
    float4 b = *(const float4*)(src + off + 4);
    short8 s;
    s[0]=(short)f2bf(a.x); s[1]=(short)f2bf(a.y); s[2]=(short)f2bf(a.z); s[3]=(short)f2bf(a.w);
    s[4]=(short)f2bf(b.x); s[5]=(short)f2bf(b.y); s[6]=(short)f2bf(b.z); s[7]=(short)f2bf(b.w);
    *(short8*)(dst + off) = s;
}

// ---------------- router ----------------
__global__ __launch_bounds__(256) void router_kernel(const float* __restrict__ x, const float* __restrict__ rgw,
                                                     const float* __restrict__ mu, const float* __restrict__ rsig,
                                                     float* __restrict__ rlog) {
    __shared__ float xs[16][65];
    __shared__ float rs[128][65];
    const int t = threadIdx.x;
    const int n0 = blockIdx.x * 16;
    const int tk = t >> 5;
    const int jj = t & 31;
    float acc[2][4] = {{0.f,0.f,0.f,0.f},{0.f,0.f,0.f,0.f}};

    for (int kc = 0; kc < H_DIM; kc += 64) {
        {
            int row = t >> 4, c4 = (t & 15) * 4;
            float4 v = *(const float4*)(x + (size_t)(n0 + row) * H_DIM + kc + c4);
            float4 m = *(const float4*)(mu + kc + c4);
            float4 r = *(const float4*)(rsig + kc + c4);
            xs[row][c4 + 0] = (v.x - m.x) * r.x;
            xs[row][c4 + 1] = (v.y - m.y) * r.y;
            xs[row][c4 + 2] = (v.z - m.z) * r.z;
            xs[row][c4 + 3] = (v.w - m.w) * r.w;
        }
        {
            int row = t >> 1, base = (t & 1) * 32;
            const float* src = rgw + (size_t)row * H_DIM + kc + base;
#pragma unroll
            for (int i = 0; i < 8; ++i) {
                float4 v = *(const float4*)(src + i * 4);
                rs[row][base + i*4 + 0] = v.x;
                rs[row][base + i*4 + 1] = v.y;
                rs[row][base + i*4 + 2] = v.z;
                rs[row][base + i*4 + 3] = v.w;
            }
        }
        __syncthreads();
#pragma unroll 4
        for (int k = 0; k < 64; ++k) {
            float x0 = xs[tk][k], x1 = xs[tk + 8][k];
            float r0 = rs[jj][k], r1 = rs[jj + 32][k], r2 = rs[jj + 64][k], r3 = rs[jj + 96][k];
            acc[0][0] += x0 * r0; acc[0][1] += x0 * r1; acc[0][2] += x0 * r2; acc[0][3] += x0 * r3;
            acc[1][0] += x1 * r0; acc[1][1] += x1 * r1; acc[1][2] += x1 * r2; acc[1][3] += x1 * r3;
        }
        __syncthreads();
    }
#pragma unroll
    for (int a = 0; a < 2; ++a)
#pragma unroll
        for (int b = 0; b < 4; ++b) {
            int n = n0 + tk + 8 * a;
            int j = jj + 32 * b;
            rlog[(size_t)(j >> 6) * (N_TOK * 64) + (size_t)n * 64 + (j & 63)] = acc[a][b];
        }
}

// ---------------- top-k ----------------
__global__ __launch_bounds__(256) void topk_kernel(const float* __restrict__ rlog,
                                                   float* __restrict__ topw, int* __restrict__ topi) {
    const int lane = threadIdx.x & 63;
    const int n = blockIdx.x * 4 + (threadIdx.x >> 6);

    float a = rlog[(size_t)n * 64 + lane];
    float b = rlog[(size_t)(N_TOK * 64) + (size_t)n * 64 + lane];
    float ma = wmax64(a);
    float lpa = a - ma - logf(wsum64(expf(a - ma)));
    float mb = wmax64(b);
    float lpb = b - mb - logf(wsum64(expf(b - mb)));

    float va = lpa, vb = lpb;
    float tva = -1e30f, tvb = -1e30f; int tia = 0, tib = 0;
    for (int it = 0; it < 16; ++it) {
        float mx = wmax64(va);
        int w = __ffsll(__ballot(va == mx)) - 1;
        if (lane == it) { tva = mx; tia = w; }
        if (lane == w) va = -1e30f;
        mx = wmax64(vb);
        w = __ffsll(__ballot(vb == mx)) - 1;
        if (lane == it) { tvb = mx; tib = w; }
        if (lane == w) vb = -1e30f;
    }
    float av = __shfl(tva, lane >> 2);
    int   ai = __shfl(tia, lane >> 2);
    int   q0 = (lane & 3) * 4;
    float c0 = av + __shfl(tvb, q0 + 0); int b0 = __shfl(tib, q0 + 0);
    float c1 = av + __shfl(tvb, q0 + 1); int b1 = __shfl(tib, q0 + 1);
    float c2 = av + __shfl(tvb, q0 + 2); int b2 = __shfl(tib, q0 + 2);
    float c3 = av + __shfl(tvb, q0 + 3); int b3 = __shfl(tib, q0 + 3);

    for (int it = 0; it < 16; ++it) {
        float lv = c0; int lq = 0;
        if (c1 > lv) { lv = c1; lq = 1; }
        if (c2 > lv) { lv = c2; lq = 2; }
        if (c3 > lv) { lv = c3; lq = 3; }
        float mx = wmax64(lv);
        int w = __ffsll(__ballot(lv == mx)) - 1;
        if (lane == w) {
            int bj;
            switch (lq) {
                case 0:  bj = b0; c0 = -1e30f; break;
                case 1:  bj = b1; c1 = -1e30f; break;
                case 2:  bj = b2; c2 = -1e30f; break;
                default: bj = b3; c3 = -1e30f; break;
            }
            topw[n * 16 + it] = expf(mx);
            topi[n * 16 + it] = ai * 64 + bj;
        }
    }
}

// ---------------- PEER experts, bf16 tables (fast path) ----------------
__global__ __launch_bounds__(256) void experts_kernel_b(const float* __restrict__ x, const unsigned short* __restrict__ de,
                                                        const unsigned short* __restrict__ ue, const float* __restrict__ topw,
                                                        const int* __restrict__ topi, float* __restrict__ out) {
    __shared__ float psum[16][4];
    const int n = blockIdx.x;
    const int t = threadIdx.x, lane = t & 63, wid = t >> 6;

    float xr[8];
    {
        float4 v0 = *(const float4*)(x + (size_t)n * H_DIM + t * 8);
        float4 v1 = *(const float4*)(x + (size_t)n * H_DIM + t * 8 + 4);
        xr[0]=v0.x; xr[1]=v0.y; xr[2]=v0.z; xr[3]=v0.w;
        xr[4]=v1.x; xr[5]=v1.y; xr[6]=v1.z; xr[7]=v1.w;
    }
    int   eidx[16];
    float ew[16];
#pragma unroll
    for (int k = 0; k < 16; ++k) { eidx[k] = topi[n * 16 + k]; ew[k] = topw[n * 16 + k]; }

    short8 uf[8];
#pragma unroll
    for (int k = 0; k < 8; ++k)
        uf[k] = *(const short8*)(ue + (size_t)eidx[k] * H_DIM + t * 8);

#pragma unroll
    for (int k = 0; k < 16; ++k) {
        short8 d = *(const short8*)(de + (size_t)eidx[k] * H_DIM + t * 8);
        float p = 0.f;
#pragma unroll
        for (int j = 0; j < 8; ++j) p += bf2f((unsigned short)d[j]) * xr[j];
        p = wsum64(p);
        if (lane == 0) psum[k][wid] = p;
    }
    __syncthreads();

    float acc[8] = {0,0,0,0,0,0,0,0};
#pragma unroll
    for (int k = 0; k < 16; ++k) {
        float h = psum[k][0] + psum[k][1] + psum[k][2] + psum[k][3];
        float coef = ew[k] * h;
        short8 u = (k < 8) ? uf[k]
                           : *(const short8*)(ue + (size_t)eidx[k] * H_DIM + t * 8);
#pragma unroll
        for (int j = 0; j < 8; ++j) acc[j] += coef * bf2f((unsigned short)u[j]);
    }
    float4 o0 = {acc[0], acc[1], acc[2], acc[3]};
    float4 o1 = {acc[4], acc[5], acc[6], acc[7]};
    *(float4*)(out + (size_t)n * H_DIM + t * 8)     = o0;
    *(float4*)(out + (size_t)n * H_DIM + t * 8 + 4) = o1;
}

// ---------------- PEER experts, f32 tables (fallback) ----------------
__global__ __launch_bounds__(256) void experts_kernel(const float* __restrict__ x, const float* __restrict__ de,
                                                      const float* __restrict__ ue, const float* __restrict__ topw,
                                                      const int* __restrict__ topi, float* __restrict__ out) {
    __shared__ float psum[16][4];
    const int n = blockIdx.x;
    const int t = threadIdx.x, lane = t & 63, wid = t >> 6;

    float xr[8];
    {
        float4 v0 = *(const float4*)(x + (size_t)n * H_DIM + t * 8);
        float4 v1 = *(const float4*)(x + (size_t)n * H_DIM + t * 8 + 4);
        xr[0]=v0.x; xr[1]=v0.y; xr[2]=v0.z; xr[3]=v0.w;
        xr[4]=v1.x; xr[5]=v1.y; xr[6]=v1.z; xr[7]=v1.w;
    }
    int   eidx[16];
    float ew[16];
#pragma unroll
    for (int k = 0; k < 16; ++k) { eidx[k] = topi[n * 16 + k]; ew[k] = topw[n * 16 + k]; }

#pragma unroll
    for (int k = 0; k < 16; ++k) {
        const float* dr = de + (size_t)eidx[k] * H_DIM + t * 8;
        float4 v0 = *(const float4*)dr;
        float4 v1 = *(const float4*)(dr + 4);
        float p = v0.x*xr[0] + v0.y*xr[1] + v0.z*xr[2] + v0.w*xr[3]
                + v1.x*xr[4] + v1.y*xr[5] + v1.z*xr[6] + v1.w*xr[7];
        p = wsum64(p);
        if (lane == 0) psum[k][wid] = p;
    }
    __syncthreads();

    float acc[8] = {0,0,0,0,0,0,0,0};
#pragma unroll
    for (int k = 0; k < 16; ++k) {
        float h = psum[k][0] + psum[k][1] + psum[k][2] + psum[k][3];
        float coef = ew[k] * h;
        const float* ur = ue + (size_t)eidx[k] * H_DIM + t * 8;
        float4 v0 = *(const float4*)ur;
        float4 v1 = *(const float4*)(ur + 4);
        acc[0] += coef * v0.x; acc[1] += coef * v0.y; acc[2] += coef * v0.z; acc[3] += coef * v0.w;
        acc[4] += coef * v1.x; acc[5] += coef * v1.y; acc[6] += coef * v1.z; acc[7] += coef * v1.w;
    }
    float4 o0 = {acc[0], acc[1], acc[2], acc[3]};
    float4 o1 = {acc[4], acc[5], acc[6], acc[7]};
    *(float4*)(out + (size_t)n * H_DIM + t * 8)     = o0;
    *(float4*)(out + (size_t)n * H_DIM + t * 8 + 4) = o1;
}

#define SWZB(row, byteoff) ((byteoff) ^ (((row) & 7) << 4))

// ========== fused gate+up GEMM: 256x128 dbuf + intra-tile PACING phases =====
// Outer ledger = round-7 proven-green dbuf (__syncthreads full drain per tile;
// stages all issue at tile top). NEW: the compute is split into 4 sub-phases
// {A+G k0 | U k0 | A+G k1 | U k1}, separated by raw s_barrier + compiler
// clobber. These barriers are SEMANTICALLY INERT (all hazards closed by the
// tile-boundary __syncthreads) — pure wave pacing so LDS-read bursts of some
// waves overlap MFMA bursts of others (m201 mechanism; kernel is LDS-overlap
// bound: 192 ds_read_b128/CU/tile ≈ 768cy vs 614cy matrix work).
#define NTGU (H_DIM / 64)

__global__ __launch_bounds__(512, 2) void gemm_gu256(const unsigned short* __restrict__ xb,
                                                     const unsigned short* __restrict__ gwb,
                                                     const unsigned short* __restrict__ uwb,
                                                     unsigned short* __restrict__ act) {
    __shared__ __attribute__((aligned(16))) short sA[2][16384];   // 256 x 64
    __shared__ __attribute__((aligned(16))) short sBg[2][8192];   // 128 x 64
    __shared__ __attribute__((aligned(16))) short sBu[2][8192];   // 128 x 64
    const int t = threadIdx.x;
    const int lane = t & 63, wid = t >> 6;
    const int wm = wid >> 1, wn = wid & 1;
    const int l15 = lane & 15, l4 = lane >> 4;
    const int bid = blockIdx.x;
    const int sw = (bid & 7) * 128 + (bid >> 3);
    const int bx = sw & 63, by = sw >> 6;
    const int row0 = by * 256, col0 = bx * 128;

    const int rseg = lane >> 3;
    const int chunk = (lane & 7) ^ rseg;
    const unsigned short* aSrc = xb  + (size_t)(row0 + wid * 8 + rseg) * H_DIM + chunk * 8;
    const unsigned short* gSrc = gwb + (size_t)(col0 + wid * 8 + rseg) * H_DIM + chunk * 8;
    const unsigned short* uSrc = uwb + (size_t)(col0 + wid * 8 + rseg) * H_DIM + chunk * 8;

    const int swzb = (l15 & 7) << 4;
    const int kx0 = (l4 * 16) ^ swzb;
    const int kx1 = (64 + l4 * 16) ^ swzb;
    const int arow = (wm * 64 + l15) * 64;
    const int brow = (wn * 64 + l15) * 64;

    f32x4 zero = {0.f, 0.f, 0.f, 0.f};
    f32x4 accg[4][4], accu[4][4];
#pragma unroll
    for (int m = 0; m < 4; ++m)
#pragma unroll
        for (int n = 0; n < 4; ++n) { accg[m][n] = zero; accu[m][n] = zero; }

    stage4<H_DIM, 64, 4096>(aSrc, &sA[0][wid * 512]);
    stage2<H_DIM, 64, 4096>(gSrc, &sBg[0][wid * 512]);
    stage2<H_DIM, 64, 4096>(uSrc, &sBu[0][wid * 512]);
    __syncthreads();

    int cur = 0;
    for (int g = 0; g < NTGU; ++g) {
        // stage next tile at tile top (max landing window; drained by the
        // tile-end __syncthreads — round-7 ledger unchanged)
        if (g + 1 < NTGU) {
            stage4<H_DIM, 64, 4096>(aSrc + (size_t)(g + 1) * 64, &sA[cur ^ 1][wid * 512]);
            stage2<H_DIM, 64, 4096>(gSrc + (size_t)(g + 1) * 64, &sBg[cur ^ 1][wid * 512]);
            stage2<H_DIM, 64, 4096>(uSrc + (size_t)(g + 1) * 64, &sBu[cur ^ 1][wid * 512]);
        }
        const short* Ac = &sA[cur][0];
        const short* Gc = &sBg[cur][0];
        const short* Uc = &sBu[cur][0];
        short8 a0[4], a1[4], bg[4], bu[4];
        // ---- P1: A k0 + G k0 reads; 16 g-MFMA k0
#pragma unroll
        for (int m = 0; m < 4; ++m) a0[m] = *(const short8*)(Ac + arow + m * 1024 + (kx0 >> 1));
#pragma unroll
        for (int n = 0; n < 4; ++n) bg[n] = *(const short8*)(Gc + brow + n * 1024 + (kx0 >> 1));
        __builtin_amdgcn_s_setprio(1);
#pragma unroll
        for (int m = 0; m < 4; ++m)
#pragma unroll
            for (int n = 0; n < 4; ++n)
                accg[m][n] = __builtin_amdgcn_mfma_f32_16x16x32_bf16(a0[m], bg[n], accg[m][n], 0, 0, 0);
        __builtin_amdgcn_s_setprio(0);
        __builtin_amdgcn_s_barrier();          // pacing only
        asm volatile("" ::: "memory");
        // ---- P2: U k0 reads; 16 u-MFMA k0 (A k0 still in regs)
#pragma unroll
        for (int n = 0; n < 4; ++n) bu[n] = *(const short8*)(Uc + brow + n * 1024 + (kx0 >> 1));
        __builtin_amdgcn_s_setprio(1);
#pragma unroll
        for (int m = 0; m < 4; ++m)
#pragma unroll
            for (int n = 0; n < 4; ++n)
                accu[m][n] = __builtin_amdgcn_mfma_f32_16x16x32_bf16(a0[m], bu[n], accu[m][n], 0, 0, 0);
        __builtin_amdgcn_s_setprio(0);
        __builtin_amdgcn_s_barrier();
        asm volatile("" ::: "memory");
        // ---- P3: A k1 + G k1 reads; 16 g-MFMA k1
#pragma unroll
        for (int m = 0; m < 4; ++m) a1[m] = *(const short8*)(Ac + arow + m * 1024 + (kx1 >> 1));
#pragma unroll
        for (int n = 0; n < 4; ++n) bg[n] = *(const short8*)(Gc + brow + n * 1024 + (kx1 >> 1));
        __builtin_amdgcn_s_setprio(1);
#pragma unroll
        for (int m = 0; m < 4; ++m)
#pragma unroll
            for (int n = 0; n < 4; ++n)
                accg[m][n] = __builtin_amdgcn_mfma_f32_16x16x32_bf16(a1[m], bg[n], accg[m][n], 0, 0, 0);
        __builtin_amdgcn_s_setprio(0);
        __builtin_amdgcn_s_barrier();
        asm volatile("" ::: "memory");
        // ---- P4: U k1 reads; 16 u-MFMA k1
#pragma unroll
        for (int n = 0; n < 4; ++n) bu[n] = *(const short8*)(Uc + brow + n * 1024 + (kx1 >> 1));
        __builtin_amdgcn_s_setprio(1);
#pragma unroll
        for (int m = 0; m < 4; ++m)
#pragma unroll
            for (int n = 0; n < 4; ++n)
                accu[m][n] = __builtin_amdgcn_mfma_f32_16x16x32_bf16(a1[m], bu[n], accu[m][n], 0, 0, 0);
        __builtin_amdgcn_s_setprio(0);
        __syncthreads();   // full drain: tile g+1 resident, all reads retired
        cur ^= 1;
    }

    const int rbase = row0 + wm * 64, cbase = col0 + wn * 64;
#pragma unroll
    for (int m = 0; m < 4; ++m)
#pragma unroll
        for (int n = 0; n < 4; ++n)
#pragma unroll
            for (int j = 0; j < 4; ++j) {
                int r = rbase + m * 16 + l4 * 4 + j;
                int c2 = cbase + n * 16 + l15;
                float gv = accg[m][n][j];
                float uv = accu[m][n][j];
                float sv = gv / (1.f + expf(-gv));
                act[(size_t)r * I_DIM + c2] = f2bf(sv * uv);
            }
}

// ========== 128x128 down GEMM (K=8192), 2-phase dbuf ledger (round-5) =======
#define NTD (I_DIM / 64)

__global__ __launch_bounds__(256, 2) void gemm_down128(const unsigned short* __restrict__ act,
                                                       const unsigned short* __restrict__ dwb,
                                                       float* __restrict__ out) {
    __shared__ __attribute__((aligned(16))) short sA[2][8192];
    __shared__ __attribute__((aligned(16))) short sB[2][8192];
    const int t = threadIdx.x;
    const int lane = t & 63, wid = t >> 6;
    const int wm = wid >> 1, wn = wid & 1;
    const int l15 = lane & 15, l4 = lane >> 4;
    const int bid = blockIdx.x;
    const int sw = (bid & 7) * 64 + (bid >> 3);
    const int bx = sw & 15, by = sw >> 4;
    const int row0 = by * 128, col0 = bx * 128;

    const int rseg = lane >> 3;
    const int chunk = (lane & 7) ^ rseg;
    const unsigned short* aSrc = act + (size_t)(row0 + wid * 8 + rseg) * I_DIM + chunk * 8;
    const unsigned short* bSrc = dwb + (size_t)(col0 + wid * 8 + rseg) * I_DIM + chunk * 8;

    const int swzb = (l15 & 7) << 4;
    const int kx0 = (l4 * 16) ^ swzb;
    const int kx1 = (64 + l4 * 16) ^ swzb;
    const int arow = (wm * 64 + l15) * 64;
    const int brow = (wn * 64 + l15) * 64;

    f32x4 zero = {0.f, 0.f, 0.f, 0.f};
    f32x4 acc[4][4];
#pragma unroll
    for (int m = 0; m < 4; ++m)
#pragma unroll
        for (int n = 0; n < 4; ++n) acc[m][n] = zero;

    stage4<I_DIM, 32, 2048>(aSrc, &sA[0][wid * 512]);
    stage4<I_DIM, 32, 2048>(bSrc, &sB[0][wid * 512]);
    __syncthreads();

    int cur = 0;
    for (int g = 0; g < NTD; ++g) {
        if (g + 1 < NTD) {
            stage4<I_DIM, 32, 2048>(aSrc + (size_t)(g + 1) * 64, &sA[cur ^ 1][wid * 512]);
            stage4<I_DIM, 32, 2048>(bSrc + (size_t)(g + 1) * 64, &sB[cur ^ 1][wid * 512]);
        }
        const short* Ac = &sA[cur][0];
        const short* Bc = &sB[cur][0];
        {
            short8 a0[4], b0[4];
#pragma unroll
            for (int m = 0; m < 4; ++m) a0[m] = *(const short8*)(Ac + arow + m * 1024 + (kx0 >> 1));
#pragma unroll
            for (int n = 0; n < 4; ++n) b0[n] = *(const short8*)(Bc + brow + n * 1024 + (kx0 >> 1));
            __builtin_amdgcn_s_setprio(1);
#pragma unroll
            for (int m = 0; m < 4; ++m)
#pragma unroll
                for (int n = 0; n < 4; ++n)
                    acc[m][n] = __builtin_amdgcn_mfma_f32_16x16x32_bf16(a0[m], b0[n], acc[m][n], 0, 0, 0);
            __builtin_amdgcn_s_setprio(0);
        }
        {
            short8 a1[4], b1[4];
#pragma unroll
            for (int m = 0; m < 4; ++m) a1[m] = *(const short8*)(Ac + arow + m * 1024 + (kx1 >> 1));
#pragma unroll
            for (int n = 0; n < 4; ++n) b1[n] = *(const short8*)(Bc + brow + n * 1024 + (kx1 >> 1));
            __builtin_amdgcn_s_setprio(1);
#pragma unroll
            for (int m = 0; m < 4; ++m)
#pragma unroll
                for (int n = 0; n < 4; ++n)
                    acc[m][n] = __builtin_amdgcn_mfma_f32_16x16x32_bf16(a1[m], b1[n], acc[m][n], 0, 0, 0);
            __builtin_amdgcn_s_setprio(0);
        }
        __syncthreads();
        cur ^= 1;
    }

    const int rbase = row0 + wm * 64, cbase = col0 + wn * 64;
#pragma unroll
    for (int m = 0; m < 4; ++m)
#pragma unroll
        for (int n = 0; n < 4; ++n)
#pragma unroll
            for (int j = 0; j < 4; ++j) {
                int r = rbase + m * 16 + l4 * 4 + j;
                int c2 = cbase + n * 16 + l15;
                out[(size_t)r * H_DIM + c2] += acc[m][n][j];
            }
}

// ================= FALLBACK PATH (round-1, f32 weights, small ws) ===========
__global__ __launch_bounds__(256) void gemm_gu(const unsigned short* __restrict__ xb,
                                               const float* __restrict__ gw, const float* __restrict__ uw,
                                               unsigned short* __restrict__ act) {
    __shared__ __attribute__((aligned(16))) short As[128 * 64];
    __shared__ __attribute__((aligned(16))) short Bg[128 * 64];
    __shared__ __attribute__((aligned(16))) short Bu[128 * 64];
    const int t = threadIdx.x;
    const int lane = t & 63, wid = t >> 6;
    const int wr = wid >> 1, wc = wid & 1;
    const int l15 = lane & 15, l4 = lane >> 4;
    const int row0 = blockIdx.y * 128;
    const int col0 = blockIdx.x * 128;
    const int srow = t >> 1, shalf = (t & 1) * 32;

    f32x4 zero = {0.f, 0.f, 0.f, 0.f};
    f32x4 accg[4][4], accu[4][4];
#pragma unroll
    for (int m = 0; m < 4; ++m)
#pragma unroll
        for (int n = 0; n < 4; ++n) { accg[m][n] = zero; accu[m][n] = zero; }

    for (int kt = 0; kt < H_DIM; kt += 64) {
        {
            const unsigned short* src = xb + (size_t)(row0 + srow) * H_DIM + kt + shalf;
#pragma unroll
            for (int i = 0; i < 4; ++i) {
                int boff = SWZB(srow, (shalf + i * 8) * 2);
                *(short8*)(As + srow * 64 + (boff >> 1)) = *(const short8*)(src + i * 8);
            }
        }
        {
            const float* g = gw + (size_t)(col0 + srow) * H_DIM + kt + shalf;
            const float* u = uw + (size_t)(col0 + srow) * H_DIM + kt + shalf;
#pragma unroll
            for (int i = 0; i < 4; ++i) {
                int boff = SWZB(srow, (shalf + i * 8) * 2);
                float4 a0 = *(const float4*)(g + i * 8);
                float4 a1 = *(const float4*)(g + i * 8 + 4);
                short8 s;
                s[0]=(short)f2bf(a0.x); s[1]=(short)f2bf(a0.y); s[2]=(short)f2bf(a0.z); s[3]=(short)f2bf(a0.w);
                s[4]=(short)f2bf(a1.x); s[5]=(short)f2bf(a1.y); s[6]=(short)f2bf(a1.z); s[7]=(short)f2bf(a1.w);
                *(short8*)(Bg + srow * 64 + (boff >> 1)) = s;
                float4 b0 = *(const float4*)(u + i * 8);
                float4 b1 = *(const float4*)(u + i * 8 + 4);
                short8 r;
                r[0]=(short)f2bf(b0.x); r[1]=(short)f2bf(b0.y); r[2]=(short)f2bf(b0.z); r[3]=(short)f2bf(b0.w);
                r[4]=(short)f2bf(b1.x); r[5]=(short)f2bf(b1.y); r[6]=(short)f2bf(b1.z); r[7]=(short)f2bf(b1.w);
                *(short8*)(Bu + srow * 64 + (boff >> 1)) = r;
            }
        }
        __syncthreads();
#pragma unroll
        for (int kk = 0; kk < 64; kk += 32) {
            short8 af[4], bgf[4], buf_[4];
#pragma unroll
            for (int m = 0; m < 4; ++m) {
                int row = wr * 64 + m * 16 + l15;
                af[m] = *(const short8*)(As + row * 64 + (SWZB(row, (kk + l4 * 8) * 2) >> 1));
            }
#pragma unroll
            for (int n = 0; n < 4; ++n) {
                int row = wc * 64 + n * 16 + l15;
                int off = row * 64 + (SWZB(row, (kk + l4 * 8) * 2) >> 1);
                bgf[n]  = *(const short8*)(Bg + off);
                buf_[n] = *(const short8*)(Bu + off);
            }
#pragma unroll
            for (int m = 0; m < 4; ++m)
#pragma unroll
                for (int n = 0; n < 4; ++n) {
                    accg[m][n] = __builtin_amdgcn_mfma_f32_16x16x32_bf16(af[m], bgf[n],  accg[m][n], 0, 0, 0);
                    accu[m][n] = __builtin_amdgcn_mfma_f32_16x16x32_bf16(af[m], buf_[n], accu[m][n], 0, 0, 0);
                }
        }
        __syncthreads();
    }
    const int rbase = row0 + wr * 64, cbase = col0 + wc * 64;
#pragma unroll
    for (int m = 0; m < 4; ++m)
#pragma unroll
        for (int n = 0; n < 4; ++n)
#pragma unroll
            for (int j = 0; j < 4; ++j) {
                int r = rbase + m * 16 + l4 * 4 + j;
                int c = cbase + n * 16 + l15;
                float gv = accg[m][n][j];
                float uv = accu[m][n][j];
                float sv = gv / (1.f + expf(-gv));
                act[(size_t)r * I_DIM + c] = f2bf(sv * uv);
            }
}

__global__ __launch_bounds__(256) void gemm_down(const unsigned short* __restrict__ act,
                                                 const float* __restrict__ dw, float* __restrict__ out) {
    __shared__ __attribute__((aligned(16))) short As[128 * 64];
    __shared__ __attribute__((aligned(16))) short Bs[128 * 64];
    const int t = threadIdx.x;
    const int lane = t & 63, wid = t >> 6;
    const int wr = wid >> 1, wc = wid & 1;
    const int l15 = lane & 15, l4 = lane >> 4;
    const int row0 = blockIdx.y * 128;
    const int col0 = blockIdx.x * 128;
    const int srow = t >> 1, shalf = (t & 1) * 32;

    f32x4 zero = {0.f, 0.f, 0.f, 0.f};
    f32x4 acc[4][4];
#pragma unroll
    for (int m = 0; m < 4; ++m)
#pragma unroll
        for (int n = 0; n < 4; ++n) acc[m][n] = zero;

    for (int kt = 0; kt < I_DIM; kt += 64) {
        {
            const unsigned short* src = act + (size_t)(row0 + srow) * I_DIM + kt + shalf;
#pragma unroll
            for (int i = 0; i < 4; ++i) {
                int boff = SWZB(srow, (shalf + i * 8) * 2);
                *(short8*)(As + srow * 64 + (boff >> 1)) = *(const short8*)(src + i * 8);
            }
        }
        {
            const float* g = dw + (size_t)(col0 + srow) * I_DIM + kt + shalf;
#pragma unroll
            for (int i = 0; i < 4; ++i) {
                int boff = SWZB(srow, (shalf + i * 8) * 2);
                float4 a0 = *(const float4*)(g + i * 8);
                float4 a1 = *(const float4*)(g + i * 8 + 4);
                short8 s;
                s[0]=(short)f2bf(a0.x); s[1]=(short)f2bf(a0.y); s[2]=(short)f2bf(a0.z); s[3]=(short)f2bf(a0.w);
                s[4]=(short)f2bf(a1.x); s[5]=(short)f2bf(a1.y); s[6]=(short)f2bf(a1.z); s[7]=(short)f2bf(a1.w);
                *(short8*)(Bs + srow * 64 + (boff >> 1)) = s;
            }
        }
        __syncthreads();
#pragma unroll
        for (int kk = 0; kk < 64; kk += 32) {
            short8 af[4], bf[4];
#pragma unroll
            for (int m = 0; m < 4; ++m) {
                int row = wr * 64 + m * 16 + l15;
                af[m] = *(const short8*)(As + row * 64 + (SWZB(row, (kk + l4 * 8) * 2) >> 1));
            }
#pragma unroll
            for (int n = 0; n < 4; ++n) {
                int row = wc * 64 + n * 16 + l15;
                bf[n] = *(const short8*)(Bs + row * 64 + (SWZB(row, (kk + l4 * 8) * 2) >> 1));
            }
#pragma unroll
            for (int m = 0; m < 4; ++m)
#pragma unroll
                for (int n = 0; n < 4; ++n)
                    acc[m][n] = __builtin_amdgcn_mfma_f32_16x16x32_bf16(af[m], bf[n], acc[m][n], 0, 0, 0);
        }
        __syncthreads();
    }
    const int rbase = row0 + wr * 64, cbase = col0 + wc * 64;
#pragma unroll
    for (int m = 0; m < 4; ++m)
#pragma unroll
        for (int n = 0; n < 4; ++n)
#pragma unroll
            for (int j = 0; j < 4; ++j) {
                int r = rbase + m * 16 + l4 * 4 + j;
                int c = cbase + n * 16 + l15;
                out[(size_t)r * H_DIM + c] += acc[m][n][j];
            }
}

extern "C" void kernel_launch(void* const* d_in, const int* in_sizes, int n_in,
                              void* d_out, int out_size, void* d_ws, size_t ws_size,
                              hipStream_t stream) {
    const float* x   = (const float*)d_in[0];
    const float* rgw = (const float*)d_in[1];
    const float* de  = (const float*)d_in[2];
    const float* ue  = (const float*)d_in[3];
    const float* gw  = (const float*)d_in[4];
    const float* uw  = (const float*)d_in[5];
    const float* dw  = (const float*)d_in[6];
    float* out = (float*)d_out;
    char* ws = (char*)d_ws;

    float* ps   = (float*)(ws + 0);
    float* pq   = (float*)(ws + 262144);
    float* mu   = (float*)(ws + 524288);
    float* rsig = (float*)(ws + 532480);
    float* topw = (float*)(ws + 540672);
    int*   topi = (int*)  (ws + 802816);
    unsigned short* xb  = (unsigned short*)(ws + 1179648);   // 16 MB
    unsigned short* act = (unsigned short*)(ws + 17956864);  // 64 MB
    unsigned short* gwb = (unsigned short*)(ws + 85065728);  // 32 MB
    unsigned short* uwb = (unsigned short*)(ws + 118620160); // 32 MB
    unsigned short* dwb = (unsigned short*)(ws + 152174592); // 32 MB
    unsigned short* deb = (unsigned short*)(ws + 185729024); // 16 MB
    unsigned short* ueb = (unsigned short*)(ws + 202506240); // 16 MB -> end 219283456
    float* rlog = out + 8388608;
    const bool fast  = ws_size >= 185729024ULL;
    const bool fast2 = ws_size >= 219283456ULL;

    bn_stats   <<<dim3(8, 32), 256, 0, stream>>>(x, ps, pq);
    bn_finalize<<<8, 256, 0, stream>>>(ps, pq, mu, rsig);
    router_kernel<<<256, 256, 0, stream>>>(x, rgw, mu, rsig, rlog);
    topk_kernel<<<1024, 256, 0, stream>>>(rlog, topw, topi);

    if (fast2) {
        cvt_all<<<36864, 256, 0, stream>>>(gw, uw, dw, de, ue, x, gwb, uwb, dwb, deb, ueb, xb);
        experts_kernel_b<<<4096, 256, 0, stream>>>(x, deb, ueb, topw, topi, out);
        gemm_gu256<<<1024, 512, 0, stream>>>(xb, gwb, uwb, act);
        gemm_down128<<<512, 256, 0, stream>>>(act, dwb, out);
    } else if (fast) {
        cvt_x<<<8192, 256, 0, stream>>>(x, xb);
        cvt_w<<<8192, 256, 0, stream>>>(gw, gwb);
        cvt_w<<<8192, 256, 0, stream>>>(uw, uwb);
        cvt_w<<<8192, 256, 0, stream>>>(dw, dwb);
        experts_kernel<<<4096, 256, 0, stream>>>(x, de, ue, topw, topi, out);
        gemm_gu256<<<1024, 512, 0, stream>>>(xb, gwb, uwb, act);
        gemm_down128<<<512, 256, 0, stream>>>(act, dwb, out);
    } else {
        cvt_x<<<8192, 256, 0, stream>>>(x, xb);
        experts_kernel<<<4096, 256, 0, stream>>>(x, de, ue, topw, topi, out);
        gemm_gu  <<<dim3(64, 32), 256, 0, stream>>>(xb, gw, uw, act);
        gemm_down<<<dim3(16, 32), 256, 0, stream>>>(act, dw, out);
    }
}

// Round 12
// 755.776 us; speedup vs baseline: 1.0467x; 1.0467x over previous
//
#include <hip/hip_runtime.h>
#include <stdint.h>

#define H_DIM 2048
#define N_TOK 4096
#define I_DIM 8192

typedef __attribute__((ext_vector_type(8))) short short8;
typedef __attribute__((ext_vector_type(4))) float f32x4;

typedef const __attribute__((address_space(1))) unsigned int* gp_t;
typedef __attribute__((address_space(3))) unsigned int* lp_t;

__device__ __forceinline__ void gload16(const unsigned short* g, short* l) {
    __builtin_amdgcn_global_load_lds((gp_t)g, (lp_t)l, 16, 0, 0);
}

__device__ __forceinline__ unsigned short f2bf(float f) {
    union { float f; unsigned int u; } c; c.f = f;
    unsigned int u = c.u;
    return (unsigned short)((u + 0x7FFFu + ((u >> 16) & 1u)) >> 16);  // RNE
}
__device__ __forceinline__ float bf2f(unsigned short u) {
    union { unsigned int i; float f; } c; c.i = ((unsigned int)u) << 16;
    return c.f;
}

__device__ __forceinline__ float wmax64(float v) {
#pragma unroll
    for (int o = 32; o > 0; o >>= 1) v = fmaxf(v, __shfl_xor(v, o));
    return v;
}
__device__ __forceinline__ float wsum64(float v) {
#pragma unroll
    for (int o = 32; o > 0; o >>= 1) v += __shfl_xor(v, o);
    return v;
}

template<int K, int RSTEP, int LSTEP>
__device__ __forceinline__ void stage4(const unsigned short* src, short* dst) {
#pragma unroll
    for (int j = 0; j < 4; ++j)
        gload16(src + (size_t)j * RSTEP * K, dst + j * LSTEP);
}
template<int K, int RSTEP, int LSTEP>
__device__ __forceinline__ void stage2(const unsigned short* src, short* dst) {
#pragma unroll
    for (int j = 0; j < 2; ++j)
        gload16(src + (size_t)j * RSTEP * K, dst + j * LSTEP);
}

// ---------------- BatchNorm statistics (deterministic 2-stage) ----------------
__global__ __launch_bounds__(256) void bn_stats(const float* __restrict__ x,
                                                float* __restrict__ ps, float* __restrict__ pq) {
    int col = blockIdx.x * 256 + threadIdx.x;
    int r0  = blockIdx.y * 128;
    float s = 0.f, q = 0.f;
    for (int r = 0; r < 128; ++r) {
        float v = x[(size_t)(r0 + r) * H_DIM + col];
        s += v; q += v * v;
    }
    ps[blockIdx.y * H_DIM + col] = s;
    pq[blockIdx.y * H_DIM + col] = q;
}

__global__ __launch_bounds__(256) void bn_finalize(const float* __restrict__ ps, const float* __restrict__ pq,
                                                   float* __restrict__ mu, float* __restrict__ rsig) {
    int c = blockIdx.x * 256 + threadIdx.x;
    float s = 0.f, q = 0.f;
    for (int i = 0; i < 32; ++i) { s += ps[i * H_DIM + c]; q += pq[i * H_DIM + c]; }
    float m = s * (1.f / N_TOK);
    float v = q * (1.f / N_TOK) - m * m;
    mu[c] = m;
    rsig[c] = rsqrtf(v + 1e-5f);
}

// ---------------- one-shot f32 -> bf16 conversion of everything -------------
__global__ __launch_bounds__(256) void cvt_all(const float* __restrict__ gw, const float* __restrict__ uw,
                                               const float* __restrict__ dw, const float* __restrict__ de,
                                               const float* __restrict__ ue, const float* __restrict__ x,
                                               unsigned short* __restrict__ gwb, unsigned short* __restrict__ uwb,
                                               unsigned short* __restrict__ dwb, unsigned short* __restrict__ deb,
                                               unsigned short* __restrict__ ueb, unsigned short* __restrict__ xb) {
    int b = blockIdx.x;
    const float* src; unsigned short* dst; size_t base;
    if      (b < 8192)  { src = gw; dst = gwb; base = (size_t)b; }
    else if (b < 16384) { src = uw; dst = uwb; base = (size_t)(b - 8192); }
    else if (b < 24576) { src = dw; dst = dwb; base = (size_t)(b - 16384); }
    else if (b < 28672) { src = de; dst = deb; base = (size_t)(b - 24576); }
    else if (b < 32768) { src = ue; dst = ueb; base = (size_t)(b - 28672); }
    else                { src = x;  dst = xb;  base = (size_t)(b - 32768); }
    size_t off = (base * 256 + threadIdx.x) * 8;
    float4 a = *(const float4*)(src + off);
    float4 c = *(const float4*)(src + off + 4);
    short8 s;
    s[0]=(short)f2bf(a.x); s[1]=(short)f2bf(a.y); s[2]=(short)f2bf(a.z); s[3]=(short)f2bf(a.w);
    s[4]=(short)f2bf(c.x); s[5]=(short)f2bf(c.y); s[6]=(short)f2bf(c.z); s[7]=(short)f2bf(c.w);
    *(short8*)(dst + off) = s;
}

// ---------------- x -> bf16 (fallback path only) ----------------
__global__ __launch_bounds__(256) void cvt_x(const float* __restrict__ x, unsigned short* __restrict__ xb) {
    size_t i = ((size_t)blockIdx.x * 256 + threadIdx.x) * 4;
    float4 v = *(const float4*)(x + i);
    uint2 o;
    o.x = (unsigned)f2bf(v.x) | ((unsigned)f2bf(v.y) << 16);
    o.y = (unsigned)f2bf(v.z) | ((unsigned)f2bf(v.w) << 16);
    *(uint2*)(xb + i) = o;
}

__global__ __launch_bounds__(256) void cvt_w(const float* __restrict__ src, unsigned short* __restrict__ dst) {
    size_t off = ((size_t)blockIdx.x * 256 + threadIdx.x) * 8;
    float4 a = *(const float4*)(src + off);
    float4 b = *(const float4*)(src + off + 4);
    short8 s;
    s[0]=(short)f2bf(a.x); s[1]=(short)f2bf(a.y); s[2]=(short)f2bf(a.z); s[3]=(short)f2bf(a.w);
    s[4]=(short)f2bf(b.x); s[5]=(short)f2bf(b.y); s[6]=(short)f2bf(b.z); s[7]=(short)f2bf(b.w);
    *(short8*)(dst + off) = s;
}

// ---------------- router ----------------
__global__ __launch_bounds__(256) void router_kernel(const float* __restrict__ x, const float* __restrict__ rgw,
                                                     const float* __restrict__ mu, const float* __restrict__ rsig,
                                                     float* __restrict__ rlog) {
    __shared__ float xs[16][65];
    __shared__ float rs[128][65];
    const int t = threadIdx.x;
    const int n0 = blockIdx.x * 16;
    const int tk = t >> 5;
    const int jj = t & 31;
    float acc[2][4] = {{0.f,0.f,0.f,0.f},{0.f,0.f,0.f,0.f}};

    for (int kc = 0; kc < H_DIM; kc += 64) {
        {
            int row = t >> 4, c4 = (t & 15) * 4;
            float4 v = *(const float4*)(x + (size_t)(n0 + row) * H_DIM + kc + c4);
            float4 m = *(const float4*)(mu + kc + c4);
            float4 r = *(const float4*)(rsig + kc + c4);
            xs[row][c4 + 0] = (v.x - m.x) * r.x;
            xs[row][c4 + 1] = (v.y - m.y) * r.y;
            xs[row][c4 + 2] = (v.z - m.z) * r.z;
            xs[row][c4 + 3] = (v.w - m.w) * r.w;
        }
        {
            int row = t >> 1, base = (t & 1) * 32;
            const float* src = rgw + (size_t)row * H_DIM + kc + base;
#pragma unroll
            for (int i = 0; i < 8; ++i) {
                float4 v = *(const float4*)(src + i * 4);
                rs[row][base + i*4 + 0] = v.x;
                rs[row][base + i*4 + 1] = v.y;
                rs[row][base + i*4 + 2] = v.z;
                rs[row][base + i*4 + 3] = v.w;
            }
        }
        __syncthreads();
#pragma unroll 4
        for (int k = 0; k < 64; ++k) {
            float x0 = xs[tk][k], x1 = xs[tk + 8][k];
            float r0 = rs[jj][k], r1 = rs[jj + 32][k], r2 = rs[jj + 64][k], r3 = rs[jj + 96][k];
            acc[0][0] += x0 * r0; acc[0][1] += x0 * r1; acc[0][2] += x0 * r2; acc[0][3] += x0 * r3;
            acc[1][0] += x1 * r0; acc[1][1] += x1 * r1; acc[1][2] += x1 * r2; acc[1][3] += x1 * r3;
        }
        __syncthreads();
    }
#pragma unroll
    for (int a = 0; a < 2; ++a)
#pragma unroll
        for (int b = 0; b < 4; ++b) {
            int n = n0 + tk + 8 * a;
            int j = jj + 32 * b;
            rlog[(size_t)(j >> 6) * (N_TOK * 64) + (size_t)n * 64 + (j & 63)] = acc[a][b];
        }
}

// ---------------- top-k ----------------
__global__ __launch_bounds__(256) void topk_kernel(const float* __restrict__ rlog,
                                                   float* __restrict__ topw, int* __restrict__ topi) {
    const int lane = threadIdx.x & 63;
    const int n = blockIdx.x * 4 + (threadIdx.x >> 6);

    float a = rlog[(size_t)n * 64 + lane];
    float b = rlog[(size_t)(N_TOK * 64) + (size_t)n * 64 + lane];
    float ma = wmax64(a);
    float lpa = a - ma - logf(wsum64(expf(a - ma)));
    float mb = wmax64(b);
    float lpb = b - mb - logf(wsum64(expf(b - mb)));

    float va = lpa, vb = lpb;
    float tva = -1e30f, tvb = -1e30f; int tia = 0, tib = 0;
    for (int it = 0; it < 16; ++it) {
        float mx = wmax64(va);
        int w = __ffsll(__ballot(va == mx)) - 1;
        if (lane == it) { tva = mx; tia = w; }
        if (lane == w) va = -1e30f;
        mx = wmax64(vb);
        w = __ffsll(__ballot(vb == mx)) - 1;
        if (lane == it) { tvb = mx; tib = w; }
        if (lane == w) vb = -1e30f;
    }
    float av = __shfl(tva, lane >> 2);
    int   ai = __shfl(tia, lane >> 2);
    int   q0 = (lane & 3) * 4;
    float c0 = av + __shfl(tvb, q0 + 0); int b0 = __shfl(tib, q0 + 0);
    float c1 = av + __shfl(tvb, q0 + 1); int b1 = __shfl(tib, q0 + 1);
    float c2 = av + __shfl(tvb, q0 + 2); int b2 = __shfl(tib, q0 + 2);
    float c3 = av + __shfl(tvb, q0 + 3); int b3 = __shfl(tib, q0 + 3);

    for (int it = 0; it < 16; ++it) {
        float lv = c0; int lq = 0;
        if (c1 > lv) { lv = c1; lq = 1; }
        if (c2 > lv) { lv = c2; lq = 2; }
        if (c3 > lv) { lv = c3; lq = 3; }
        float mx = wmax64(lv);
        int w = __ffsll(__ballot(lv == mx)) - 1;
        if (lane == w) {
            int bj;
            switch (lq) {
                case 0:  bj = b0; c0 = -1e30f; break;
                case 1:  bj = b1; c1 = -1e30f; break;
                case 2:  bj = b2; c2 = -1e30f; break;
                default: bj = b3; c3 = -1e30f; break;
            }
            topw[n * 16 + it] = expf(mx);
            topi[n * 16 + it] = ai * 64 + bj;
        }
    }
}

// ---------------- PEER experts, bf16 tables, ONE WAVE PER TOKEN -------------
// 4 tokens/block (256 thr), no __syncthreads, no LDS: each wave owns a token.
// Lane covers 4 chunks of 8 elems (chunk j at j*512 + lane*8 -> each chunk
// load is 1KB-contiguous across the wave, coalesced). All 16 k-iterations
// independent -> deep gather pipelining; h via in-wave wsum64 only.
__global__ __launch_bounds__(256) void experts_kernel_w(const float* __restrict__ x, const unsigned short* __restrict__ de,
                                                        const unsigned short* __restrict__ ue, const float* __restrict__ topw,
                                                        const int* __restrict__ topi, float* __restrict__ out) {
    const int wid = threadIdx.x >> 6, lane = threadIdx.x & 63;
    const int n = blockIdx.x * 4 + wid;
    const int co = lane * 8;           // chunk-local column offset

    float xr[4][8];
#pragma unroll
    for (int j = 0; j < 4; ++j) {
        float4 v0 = *(const float4*)(x + (size_t)n * H_DIM + j * 512 + co);
        float4 v1 = *(const float4*)(x + (size_t)n * H_DIM + j * 512 + co + 4);
        xr[j][0]=v0.x; xr[j][1]=v0.y; xr[j][2]=v0.z; xr[j][3]=v0.w;
        xr[j][4]=v1.x; xr[j][5]=v1.y; xr[j][6]=v1.z; xr[j][7]=v1.w;
    }
    int   eidx[16];
    float ew[16];
#pragma unroll
    for (int k = 0; k < 16; ++k) { eidx[k] = topi[n * 16 + k]; ew[k] = topw[n * 16 + k]; }

    float h[16];
#pragma unroll
    for (int k = 0; k < 16; ++k) {
        const unsigned short* dr = de + (size_t)eidx[k] * H_DIM;
        float p = 0.f;
#pragma unroll
        for (int j = 0; j < 4; ++j) {
            short8 d = *(const short8*)(dr + j * 512 + co);
#pragma unroll
            for (int e = 0; e < 8; ++e) p += bf2f((unsigned short)d[e]) * xr[j][e];
        }
        h[k] = wsum64(p);
    }

    float acc[4][8];
#pragma unroll
    for (int j = 0; j < 4; ++j)
#pragma unroll
        for (int e = 0; e < 8; ++e) acc[j][e] = 0.f;
#pragma unroll
    for (int k = 0; k < 16; ++k) {
        float coef = ew[k] * h[k];
        const unsigned short* ur = ue + (size_t)eidx[k] * H_DIM;
#pragma unroll
        for (int j = 0; j < 4; ++j) {
            short8 u = *(const short8*)(ur + j * 512 + co);
#pragma unroll
            for (int e = 0; e < 8; ++e) acc[j][e] += coef * bf2f((unsigned short)u[e]);
        }
    }
#pragma unroll
    for (int j = 0; j < 4; ++j) {
        float4 o0 = {acc[j][0], acc[j][1], acc[j][2], acc[j][3]};
        float4 o1 = {acc[j][4], acc[j][5], acc[j][6], acc[j][7]};
        *(float4*)(out + (size_t)n * H_DIM + j * 512 + co)     = o0;
        *(float4*)(out + (size_t)n * H_DIM + j * 512 + co + 4) = o1;
    }
}

// ---------------- PEER experts, f32 tables (fallback) ----------------
__global__ __launch_bounds__(256) void experts_kernel(const float* __restrict__ x, const float* __restrict__ de,
                                                      const float* __restrict__ ue, const float* __restrict__ topw,
                                                      const int* __restrict__ topi, float* __restrict__ out) {
    __shared__ float psum[16][4];
    const int n = blockIdx.x;
    const int t = threadIdx.x, lane = t & 63, wid = t >> 6;

    float xr[8];
    {
        float4 v0 = *(const float4*)(x + (size_t)n * H_DIM + t * 8);
        float4 v1 = *(const float4*)(x + (size_t)n * H_DIM + t * 8 + 4);
        xr[0]=v0.x; xr[1]=v0.y; xr[2]=v0.z; xr[3]=v0.w;
        xr[4]=v1.x; xr[5]=v1.y; xr[6]=v1.z; xr[7]=v1.w;
    }
    int   eidx[16];
    float ew[16];
#pragma unroll
    for (int k = 0; k < 16; ++k) { eidx[k] = topi[n * 16 + k]; ew[k] = topw[n * 16 + k]; }

#pragma unroll
    for (int k = 0; k < 16; ++k) {
        const float* dr = de + (size_t)eidx[k] * H_DIM + t * 8;
        float4 v0 = *(const float4*)dr;
        float4 v1 = *(const float4*)(dr + 4);
        float p = v0.x*xr[0] + v0.y*xr[1] + v0.z*xr[2] + v0.w*xr[3]
                + v1.x*xr[4] + v1.y*xr[5] + v1.z*xr[6] + v1.w*xr[7];
        p = wsum64(p);
        if (lane == 0) psum[k][wid] = p;
    }
    __syncthreads();

    float acc[8] = {0,0,0,0,0,0,0,0};
#pragma unroll
    for (int k = 0; k < 16; ++k) {
        float h = psum[k][0] + psum[k][1] + psum[k][2] + psum[k][3];
        float coef = ew[k] * h;
        const float* ur = ue + (size_t)eidx[k] * H_DIM + t * 8;
        float4 v0 = *(const float4*)ur;
        float4 v1 = *(const float4*)(ur + 4);
        acc[0] += coef * v0.x; acc[1] += coef * v0.y; acc[2] += coef * v0.z; acc[3] += coef * v0.w;
        acc[4] += coef * v1.x; acc[5] += coef * v1.y; acc[6] += coef * v1.z; acc[7] += coef * v1.w;
    }
    float4 o0 = {acc[0], acc[1], acc[2], acc[3]};
    float4 o1 = {acc[4], acc[5], acc[6], acc[7]};
    *(float4*)(out + (size_t)n * H_DIM + t * 8)     = o0;
    *(float4*)(out + (size_t)n * H_DIM + t * 8 + 4) = o1;
}

#define SWZB(row, byteoff) ((byteoff) ^ (((row) & 7) << 4))

// ========== fused gate+up GEMM: 256x128 tile, dbuf 2-phase ledger ===========
// (round-7 proven green; at 2-barrier-structure ceiling ~851 TF. Pacing
// barriers (r11) and counted-vmcnt variants (r8/r10) all null or negative —
// do not re-add without the full 8-phase rotation.)
#define NTGU (H_DIM / 64)

__global__ __launch_bounds__(512, 2) void gemm_gu256(const unsigned short* __restrict__ xb,
                                                     const unsigned short* __restrict__ gwb,
                                                     const unsigned short* __restrict__ uwb,
                                                     unsigned short* __restrict__ act) {
    __shared__ __attribute__((aligned(16))) short sA[2][16384];   // 256 x 64
    __shared__ __attribute__((aligned(16))) short sBg[2][8192];   // 128 x 64
    __shared__ __attribute__((aligned(16))) short sBu[2][8192];   // 128 x 64
    const int t = threadIdx.x;
    const int lane = t & 63, wid = t >> 6;
    const int wm = wid >> 1, wn = wid & 1;
    const int l15 = lane & 15, l4 = lane >> 4;
    const int bid = blockIdx.x;
    const int sw = (bid & 7) * 128 + (bid >> 3);
    const int bx = sw & 63, by = sw >> 6;
    const int row0 = by * 256, col0 = bx * 128;

    const int rseg = lane >> 3;
    const int chunk = (lane & 7) ^ rseg;
    const unsigned short* aSrc = xb  + (size_t)(row0 + wid * 8 + rseg) * H_DIM + chunk * 8;
    const unsigned short* gSrc = gwb + (size_t)(col0 + wid * 8 + rseg) * H_DIM + chunk * 8;
    const unsigned short* uSrc = uwb + (size_t)(col0 + wid * 8 + rseg) * H_DIM + chunk * 8;

    const int swzb = (l15 & 7) << 4;
    const int kx0 = (l4 * 16) ^ swzb;
    const int kx1 = (64 + l4 * 16) ^ swzb;
    const int arow = (wm * 64 + l15) * 64;
    const int brow = (wn * 64 + l15) * 64;

    f32x4 zero = {0.f, 0.f, 0.f, 0.f};
    f32x4 accg[4][4], accu[4][4];
#pragma unroll
    for (int m = 0; m < 4; ++m)
#pragma unroll
        for (int n = 0; n < 4; ++n) { accg[m][n] = zero; accu[m][n] = zero; }

    stage4<H_DIM, 64, 4096>(aSrc, &sA[0][wid * 512]);
    stage2<H_DIM, 64, 4096>(gSrc, &sBg[0][wid * 512]);
    stage2<H_DIM, 64, 4096>(uSrc, &sBu[0][wid * 512]);
    __syncthreads();

    int cur = 0;
    for (int g = 0; g < NTGU; ++g) {
        if (g + 1 < NTGU) {
            stage4<H_DIM, 64, 4096>(aSrc + (size_t)(g + 1) * 64, &sA[cur ^ 1][wid * 512]);
            stage2<H_DIM, 64, 4096>(gSrc + (size_t)(g + 1) * 64, &sBg[cur ^ 1][wid * 512]);
            stage2<H_DIM, 64, 4096>(uSrc + (size_t)(g + 1) * 64, &sBu[cur ^ 1][wid * 512]);
        }
        const short* Ac = &sA[cur][0];
        const short* Gc = &sBg[cur][0];
        const short* Uc = &sBu[cur][0];
        {
            short8 a0[4], bg0[4], bu0[4];
#pragma unroll
            for (int m = 0; m < 4; ++m) a0[m]  = *(const short8*)(Ac + arow + m * 1024 + (kx0 >> 1));
#pragma unroll
            for (int n = 0; n < 4; ++n) bg0[n] = *(const short8*)(Gc + brow + n * 1024 + (kx0 >> 1));
#pragma unroll
            for (int n = 0; n < 4; ++n) bu0[n] = *(const short8*)(Uc + brow + n * 1024 + (kx0 >> 1));
            __builtin_amdgcn_s_setprio(1);
#pragma unroll
            for (int m = 0; m < 4; ++m)
#pragma unroll
                for (int n = 0; n < 4; ++n) {
                    accg[m][n] = __builtin_amdgcn_mfma_f32_16x16x32_bf16(a0[m], bg0[n], accg[m][n], 0, 0, 0);
                    accu[m][n] = __builtin_amdgcn_mfma_f32_16x16x32_bf16(a0[m], bu0[n], accu[m][n], 0, 0, 0);
                }
            __builtin_amdgcn_s_setprio(0);
        }
        {
            short8 a1[4], bg1[4], bu1[4];
#pragma unroll
            for (int m = 0; m < 4; ++m) a1[m]  = *(const short8*)(Ac + arow + m * 1024 + (kx1 >> 1));
#pragma unroll
            for (int n = 0; n < 4; ++n) bg1[n] = *(const short8*)(Gc + brow + n * 1024 + (kx1 >> 1));
#pragma unroll
            for (int n = 0; n < 4; ++n) bu1[n] = *(const short8*)(Uc + brow + n * 1024 + (kx1 >> 1));
            __builtin_amdgcn_s_setprio(1);
#pragma unroll
            for (int m = 0; m < 4; ++m)
#pragma unroll
                for (int n = 0; n < 4; ++n) {
                    accg[m][n] = __builtin_amdgcn_mfma_f32_16x16x32_bf16(a1[m], bg1[n], accg[m][n], 0, 0, 0);
                    accu[m][n] = __builtin_amdgcn_mfma_f32_16x16x32_bf16(a1[m], bu1[n], accu[m][n], 0, 0, 0);
                }
            __builtin_amdgcn_s_setprio(0);
        }
        __syncthreads();
        cur ^= 1;
    }

    const int rbase = row0 + wm * 64, cbase = col0 + wn * 64;
#pragma unroll
    for (int m = 0; m < 4; ++m)
#pragma unroll
        for (int n = 0; n < 4; ++n)
#pragma unroll
            for (int j = 0; j < 4; ++j) {
                int r = rbase + m * 16 + l4 * 4 + j;
                int c2 = cbase + n * 16 + l15;
                float gv = accg[m][n][j];
                float uv = accu[m][n][j];
                float sv = gv / (1.f + expf(-gv));
                act[(size_t)r * I_DIM + c2] = f2bf(sv * uv);
            }
}

// ========== 128x128 down GEMM (K=8192), 2-phase dbuf ledger (round-5) =======
#define NTD (I_DIM / 64)

__global__ __launch_bounds__(256, 2) void gemm_down128(const unsigned short* __restrict__ act,
                                                       const unsigned short* __restrict__ dwb,
                                                       float* __restrict__ out) {
    __shared__ __attribute__((aligned(16))) short sA[2][8192];
    __shared__ __attribute__((aligned(16))) short sB[2][8192];
    const int t = threadIdx.x;
    const int lane = t & 63, wid = t >> 6;
    const int wm = wid >> 1, wn = wid & 1;
    const int l15 = lane & 15, l4 = lane >> 4;
    const int bid = blockIdx.x;
    const int sw = (bid & 7) * 64 + (bid >> 3);
    const int bx = sw & 15, by = sw >> 4;
    const int row0 = by * 128, col0 = bx * 128;

    const int rseg = lane >> 3;
    const int chunk = (lane & 7) ^ rseg;
    const unsigned short* aSrc = act + (size_t)(row0 + wid * 8 + rseg) * I_DIM + chunk * 8;
    const unsigned short* bSrc = dwb + (size_t)(col0 + wid * 8 + rseg) * I_DIM + chunk * 8;

    const int swzb = (l15 & 7) << 4;
    const int kx0 = (l4 * 16) ^ swzb;
    const int kx1 = (64 + l4 * 16) ^ swzb;
    const int arow = (wm * 64 + l15) * 64;
    const int brow = (wn * 64 + l15) * 64;

    f32x4 zero = {0.f, 0.f, 0.f, 0.f};
    f32x4 acc[4][4];
#pragma unroll
    for (int m = 0; m < 4; ++m)
#pragma unroll
        for (int n = 0; n < 4; ++n) acc[m][n] = zero;

    stage4<I_DIM, 32, 2048>(aSrc, &sA[0][wid * 512]);
    stage4<I_DIM, 32, 2048>(bSrc, &sB[0][wid * 512]);
    __syncthreads();

    int cur = 0;
    for (int g = 0; g < NTD; ++g) {
        if (g + 1 < NTD) {
            stage4<I_DIM, 32, 2048>(aSrc + (size_t)(g + 1) * 64, &sA[cur ^ 1][wid * 512]);
            stage4<I_DIM, 32, 2048>(bSrc + (size_t)(g + 1) * 64, &sB[cur ^ 1][wid * 512]);
        }
        const short* Ac = &sA[cur][0];
        const short* Bc = &sB[cur][0];
        {
            short8 a0[4], b0[4];
#pragma unroll
            for (int m = 0; m < 4; ++m) a0[m] = *(const short8*)(Ac + arow + m * 1024 + (kx0 >> 1));
#pragma unroll
            for (int n = 0; n < 4; ++n) b0[n] = *(const short8*)(Bc + brow + n * 1024 + (kx0 >> 1));
            __builtin_amdgcn_s_setprio(1);
#pragma unroll
            for (int m = 0; m < 4; ++m)
#pragma unroll
                for (int n = 0; n < 4; ++n)
                    acc[m][n] = __builtin_amdgcn_mfma_f32_16x16x32_bf16(a0[m], b0[n], acc[m][n], 0, 0, 0);
            __builtin_amdgcn_s_setprio(0);
        }
        {
            short8 a1[4], b1[4];
#pragma unroll
            for (int m = 0; m < 4; ++m) a1[m] = *(const short8*)(Ac + arow + m * 1024 + (kx1 >> 1));
#pragma unroll
            for (int n = 0; n < 4; ++n) b1[n] = *(const short8*)(Bc + brow + n * 1024 + (kx1 >> 1));
            __builtin_amdgcn_s_setprio(1);
#pragma unroll
            for (int m = 0; m < 4; ++m)
#pragma unroll
                for (int n = 0; n < 4; ++n)
                    acc[m][n] = __builtin_amdgcn_mfma_f32_16x16x32_bf16(a1[m], b1[n], acc[m][n], 0, 0, 0);
            __builtin_amdgcn_s_setprio(0);
        }
        __syncthreads();
        cur ^= 1;
    }

    const int rbase = row0 + wm * 64, cbase = col0 + wn * 64;
#pragma unroll
    for (int m = 0; m < 4; ++m)
#pragma unroll
        for (int n = 0; n < 4; ++n)
#pragma unroll
            for (int j = 0; j < 4; ++j) {
                int r = rbase + m * 16 + l4 * 4 + j;
                int c2 = cbase + n * 16 + l15;
                out[(size_t)r * H_DIM + c2] += acc[m][n][j];
            }
}

// ================= FALLBACK PATH (round-1, f32 weights, small ws) ===========
__global__ __launch_bounds__(256) void gemm_gu(const unsigned short* __restrict__ xb,
                                               const float* __restrict__ gw, const float* __restrict__ uw,
                                               unsigned short* __restrict__ act) {
    __shared__ __attribute__((aligned(16))) short As[128 * 64];
    __shared__ __attribute__((aligned(16))) short Bg[128 * 64];
    __shared__ __attribute__((aligned(16))) short Bu[128 * 64];
    const int t = threadIdx.x;
    const int lane = t & 63, wid = t >> 6;
    const int wr = wid >> 1, wc = wid & 1;
    const int l15 = lane & 15, l4 = lane >> 4;
    const int row0 = blockIdx.y * 128;
    const int col0 = blockIdx.x * 128;
    const int srow = t >> 1, shalf = (t & 1) * 32;

    f32x4 zero = {0.f, 0.f, 0.f, 0.f};
    f32x4 accg[4][4], accu[4][4];
#pragma unroll
    for (int m = 0; m < 4; ++m)
#pragma unroll
        for (int n = 0; n < 4; ++n) { accg[m][n] = zero; accu[m][n] = zero; }

    for (int kt = 0; kt < H_DIM; kt += 64) {
        {
            const unsigned short* src = xb + (size_t)(row0 + srow) * H_DIM + kt + shalf;
#pragma unroll
            for (int i = 0; i < 4; ++i) {
                int boff = SWZB(srow, (shalf + i * 8) * 2);
                *(short8*)(As + srow * 64 + (boff >> 1)) = *(const short8*)(src + i * 8);
            }
        }
        {
            const float* g = gw + (size_t)(col0 + srow) * H_DIM + kt + shalf;
            const float* u = uw + (size_t)(col0 + srow) * H_DIM + kt + shalf;
#pragma unroll
            for (int i = 0; i < 4; ++i) {
                int boff = SWZB(srow, (shalf + i * 8) * 2);
                float4 a0 = *(const float4*)(g + i * 8);
                float4 a1 = *(const float4*)(g + i * 8 + 4);
                short8 s;
                s[0]=(short)f2bf(a0.x); s[1]=(short)f2bf(a0.y); s[2]=(short)f2bf(a0.z); s[3]=(short)f2bf(a0.w);
                s[4]=(short)f2bf(a1.x); s[5]=(short)f2bf(a1.y); s[6]=(short)f2bf(a1.z); s[7]=(short)f2bf(a1.w);
                *(short8*)(Bg + srow * 64 + (boff >> 1)) = s;
                float4 b0 = *(const float4*)(u + i * 8);
                float4 b1 = *(const float4*)(u + i * 8 + 4);
                short8 r;
                r[0]=(short)f2bf(b0.x); r[1]=(short)f2bf(b0.y); r[2]=(short)f2bf(b0.z); r[3]=(short)f2bf(b0.w);
                r[4]=(short)f2bf(b1.x); r[5]=(short)f2bf(b1.y); r[6]=(short)f2bf(b1.z); r[7]=(short)f2bf(b1.w);
                *(short8*)(Bu + srow * 64 + (boff >> 1)) = r;
            }
        }
        __syncthreads();
#pragma unroll
        for (int kk = 0; kk < 64; kk += 32) {
            short8 af[4], bgf[4], buf_[4];
#pragma unroll
            for (int m = 0; m < 4; ++m) {
                int row = wr * 64 + m * 16 + l15;
                af[m] = *(const short8*)(As + row * 64 + (SWZB(row, (kk + l4 * 8) * 2) >> 1));
            }
#pragma unroll
            for (int n = 0; n < 4; ++n) {
                int row = wc * 64 + n * 16 + l15;
                int off = row * 64 + (SWZB(row, (kk + l4 * 8) * 2) >> 1);
                bgf[n]  = *(const short8*)(Bg + off);
                buf_[n] = *(const short8*)(Bu + off);
            }
#pragma unroll
            for (int m = 0; m < 4; ++m)
#pragma unroll
                for (int n = 0; n < 4; ++n) {
                    accg[m][n] = __builtin_amdgcn_mfma_f32_16x16x32_bf16(af[m], bgf[n],  accg[m][n], 0, 0, 0);
                    accu[m][n] = __builtin_amdgcn_mfma_f32_16x16x32_bf16(af[m], buf_[n], accu[m][n], 0, 0, 0);
                }
        }
        __syncthreads();
    }
    const int rbase = row0 + wr * 64, cbase = col0 + wc * 64;
#pragma unroll
    for (int m = 0; m < 4; ++m)
#pragma unroll
        for (int n = 0; n < 4; ++n)
#pragma unroll
            for (int j = 0; j < 4; ++j) {
                int r = rbase + m * 16 + l4 * 4 + j;
                int c = cbase + n * 16 + l15;
                float gv = accg[m][n][j];
                float uv = accu[m][n][j];
                float sv = gv / (1.f + expf(-gv));
                act[(size_t)r * I_DIM + c] = f2bf(sv * uv);
            }
}

__global__ __launch_bounds__(256) void gemm_down(const unsigned short* __restrict__ act,
                                                 const float* __restrict__ dw, float* __restrict__ out) {
    __shared__ __attribute__((aligned(16))) short As[128 * 64];
    __shared__ __attribute__((aligned(16))) short Bs[128 * 64];
    const int t = threadIdx.x;
    const int lane = t & 63, wid = t >> 6;
    const int wr = wid >> 1, wc = wid & 1;
    const int l15 = lane & 15, l4 = lane >> 4;
    const int row0 = blockIdx.y * 128;
    const int col0 = blockIdx.x * 128;
    const int srow = t >> 1, shalf = (t & 1) * 32;

    f32x4 zero = {0.f, 0.f, 0.f, 0.f};
    f32x4 acc[4][4];
#pragma unroll
    for (int m = 0; m < 4; ++m)
#pragma unroll
        for (int n = 0; n < 4; ++n) acc[m][n] = zero;

    for (int kt = 0; kt < I_DIM; kt += 64) {
        {
            const unsigned short* src = act + (size_t)(row0 + srow) * I_DIM + kt + shalf;
#pragma unroll
            for (int i = 0; i < 4; ++i) {
                int boff = SWZB(srow, (shalf + i * 8) * 2);
                *(short8*)(As + srow * 64 + (boff >> 1)) = *(const short8*)(src + i * 8);
            }
        }
        {
            const float* g = dw + (size_t)(col0 + srow) * I_DIM + kt + shalf;
#pragma unroll
            for (int i = 0; i < 4; ++i) {
                int boff = SWZB(srow, (shalf + i * 8) * 2);
                float4 a0 = *(const float4*)(g + i * 8);
                float4 a1 = *(const float4*)(g + i * 8 + 4);
                short8 s;
                s[0]=(short)f2bf(a0.x); s[1]=(short)f2bf(a0.y); s[2]=(short)f2bf(a0.z); s[3]=(short)f2bf(a0.w);
                s[4]=(short)f2bf(a1.x); s[5]=(short)f2bf(a1.y); s[6]=(short)f2bf(a1.z); s[7]=(short)f2bf(a1.w);
                *(short8*)(Bs + srow * 64 + (boff >> 1)) = s;
            }
        }
        __syncthreads();
#pragma unroll
        for (int kk = 0; kk < 64; kk += 32) {
            short8 af[4], bf[4];
#pragma unroll
            for (int m = 0; m < 4; ++m) {
                int row = wr * 64 + m * 16 + l15;
                af[m] = *(const short8*)(As + row * 64 + (SWZB(row, (kk + l4 * 8) * 2) >> 1));
            }
#pragma unroll
            for (int n = 0; n < 4; ++n) {
                int row = wc * 64 + n * 16 + l15;
                bf[n] = *(const short8*)(Bs + row * 64 + (SWZB(row, (kk + l4 * 8) * 2) >> 1));
            }
#pragma unroll
            for (int m = 0; m < 4; ++m)
#pragma unroll
                for (int n = 0; n < 4; ++n)
                    acc[m][n] = __builtin_amdgcn_mfma_f32_16x16x32_bf16(af[m], bf[n], acc[m][n], 0, 0, 0);
        }
        __syncthreads();
    }
    const int rbase = row0 + wr * 64, cbase = col0 + wc * 64;
#pragma unroll
    for (int m = 0; m < 4; ++m)
#pragma unroll
        for (int n = 0; n < 4; ++n)
#pragma unroll
            for (int j = 0; j < 4; ++j) {
                int r = rbase + m * 16 + l4 * 4 + j;
                int c = cbase + n * 16 + l15;
                out[(size_t)r * H_DIM + c] += acc[m][n][j];
            }
}

extern "C" void kernel_launch(void* const* d_in, const int* in_sizes, int n_in,
                              void* d_out, int out_size, void* d_ws, size_t ws_size,
                              hipStream_t stream) {
    const float* x   = (const float*)d_in[0];
    const float* rgw = (const float*)d_in[1];
    const float* de  = (const float*)d_in[2];
    const float* ue  = (const float*)d_in[3];
    const float* gw  = (const float*)d_in[4];
    const float* uw  = (const float*)d_in[5];
    const float* dw  = (const float*)d_in[6];
    float* out = (float*)d_out;
    char* ws = (char*)d_ws;

    float* ps   = (float*)(ws + 0);
    float* pq   = (float*)(ws + 262144);
    float* mu   = (float*)(ws + 524288);
    float* rsig = (float*)(ws + 532480);
    float* topw = (float*)(ws + 540672);
    int*   topi = (int*)  (ws + 802816);
    unsigned short* xb  = (unsigned short*)(ws + 1179648);   // 16 MB
    unsigned short* act = (unsigned short*)(ws + 17956864);  // 64 MB
    unsigned short* gwb = (unsigned short*)(ws + 85065728);  // 32 MB
    unsigned short* uwb = (unsigned short*)(ws + 118620160); // 32 MB
    unsigned short* dwb = (unsigned short*)(ws + 152174592); // 32 MB
    unsigned short* deb = (unsigned short*)(ws + 185729024); // 16 MB
    unsigned short* ueb = (unsigned short*)(ws + 202506240); // 16 MB -> end 219283456
    float* rlog = out + 8388608;
    const bool fast  = ws_size >= 185729024ULL;
    const bool fast2 = ws_size >= 219283456ULL;

    bn_stats   <<<dim3(8, 32), 256, 0, stream>>>(x, ps, pq);
    bn_finalize<<<8, 256, 0, stream>>>(ps, pq, mu, rsig);
    router_kernel<<<256, 256, 0, stream>>>(x, rgw, mu, rsig, rlog);
    topk_kernel<<<1024, 256, 0, stream>>>(rlog, topw, topi);

    if (fast2) {
        cvt_all<<<36864, 256, 0, stream>>>(gw, uw, dw, de, ue, x, gwb, uwb, dwb, deb, ueb, xb);
        experts_kernel_w<<<1024, 256, 0, stream>>>(x, deb, ueb, topw, topi, out);
        gemm_gu256<<<1024, 512, 0, stream>>>(xb, gwb, uwb, act);
        gemm_down128<<<512, 256, 0, stream>>>(act, dwb, out);
    } else if (fast) {
        cvt_x<<<8192, 256, 0, stream>>>(x, xb);
        cvt_w<<<8192, 256, 0, stream>>>(gw, gwb);
        cvt_w<<<8192, 256, 0, stream>>>(uw, uwb);
        cvt_w<<<8192, 256, 0, stream>>>(dw, dwb);
        experts_kernel<<<4096, 256, 0, stream>>>(x, de, ue, topw, topi, out);
        gemm_gu256<<<1024, 512, 0, stream>>>(xb, gwb, uwb, act);
        gemm_down128<<<512, 256, 0, stream>>>(act, dwb, out);
    } else {
        cvt_x<<<8192, 256, 0, stream>>>(x, xb);
        experts_kernel<<<4096, 256, 0, stream>>>(x, de, ue, topw, topi, out);
        gemm_gu  <<<dim3(64, 32), 256, 0, stream>>>(xb, gw, uw, act);
        gemm_down<<<dim3(16, 32), 256, 0, stream>>>(act, dw, out);
    }
}